// Round 1
// baseline (1812.072 us; speedup 1.0000x reference)
//
#include <hip/hip_runtime.h>
#include <cstdint>
#include <cstddef>
#include <cmath>

#define N_TOK 2048
#define HDIM  2048
#define NEXP  16
#define IDIM  1024
#define SIDIM 2048

#define BM 64
#define BN 64
#define BK 16
#define NTHREADS 256

// ---------------------------------------------------------------- router ----
__global__ __launch_bounds__(NTHREADS)
void router_kernel(const float* __restrict__ x,
                   const float* __restrict__ rw,
                   float* __restrict__ logits_out,
                   int* __restrict__ cnt,
                   int* __restrict__ tok_list,
                   float* __restrict__ wt_list)
{
    const int n = blockIdx.x;
    const int tid = threadIdx.x;
    const float* xr = x + (size_t)n * HDIM;

    float acc[NEXP];
#pragma unroll
    for (int e = 0; e < NEXP; ++e) acc[e] = 0.f;

    for (int h = tid; h < HDIM; h += NTHREADS) {
        float xv = xr[h];
#pragma unroll
        for (int e = 0; e < NEXP; ++e) acc[e] += xv * rw[(size_t)e * HDIM + h];
    }

    __shared__ float red[NEXP][NTHREADS];
#pragma unroll
    for (int e = 0; e < NEXP; ++e) red[e][tid] = acc[e];
    __syncthreads();
    for (int s = NTHREADS / 2; s > 0; s >>= 1) {
        if (tid < s) {
#pragma unroll
            for (int e = 0; e < NEXP; ++e) red[e][tid] += red[e][tid + s];
        }
        __syncthreads();
    }

    if (tid < NEXP) logits_out[(size_t)n * NEXP + tid] = red[tid][0];

    if (tid == 0) {
        float l[NEXP];
#pragma unroll
        for (int e = 0; e < NEXP; ++e) l[e] = red[e][0];
        // top-2 on logits == top-2 on softmax probs (monotonic); ties -> lowest idx
        int e0 = 0;
#pragma unroll
        for (int e = 1; e < NEXP; ++e) if (l[e] > l[e0]) e0 = e;
        int e1 = (e0 == 0) ? 1 : 0;
#pragma unroll
        for (int e = 0; e < NEXP; ++e)
            if (e != e0 && l[e] > l[e1]) e1 = e;
        // renormalized top-2 weights: exp(l0)/(exp(l0)+exp(l1)), etc.
        float t = expf(l[e1] - l[e0]);
        float s = 1.f + t;
        float rw0 = 1.f / s;
        float rw1 = t / s;
        int p0 = atomicAdd(&cnt[e0], 1);
        tok_list[e0 * N_TOK + p0] = n;
        wt_list[e0 * N_TOK + p0] = rw0;
        int p1 = atomicAdd(&cnt[e1], 1);
        tok_list[e1 * N_TOK + p1] = n;
        wt_list[e1 * N_TOK + p1] = rw1;
    }
}

__global__ void prefix_kernel(const int* __restrict__ cnt, int* __restrict__ base)
{
    if (threadIdx.x == 0) {
        int s = 0;
        for (int e = 0; e < NEXP; ++e) { base[e] = s; s += cnt[e]; }
    }
}

// --------------------------------------------- fused dual GEMM + SwiGLU ----
// Y[row, n] = silu(X@Wg)[row,n] * (X@Wu)[row,n]
// gathered (tok_list != nullptr): rows are expert-local slots, X rows via
// tok_list, output rows compacted at base[e]; else identity over N_TOK rows.
__global__ __launch_bounds__(NTHREADS)
void dual_swiglu_kernel(const float* __restrict__ X,
                        const float* __restrict__ WgAll,
                        const float* __restrict__ WuAll,
                        float* __restrict__ Y,
                        const int* __restrict__ cnt,
                        const int* __restrict__ base,
                        const int* __restrict__ tok_list,
                        int Icols)
{
    const int e  = blockIdx.z;
    const int m0 = blockIdx.y * BM;
    const int n0 = blockIdx.x * BN;
    const bool gathered = (tok_list != nullptr);
    const int M = gathered ? cnt[e] : N_TOK;
    if (m0 >= M) return;
    const float* Wg = WgAll + (size_t)e * HDIM * Icols;
    const float* Wu = WuAll + (size_t)e * HDIM * Icols;
    const int yb = gathered ? base[e] : 0;

    __shared__ float Xs[BK][BM + 4];
    __shared__ float Gs[BK][BN + 4];
    __shared__ float Us[BK][BN + 4];

    const int tid = threadIdx.x;
    const int tx = tid & 15;
    const int ty = tid >> 4;

    // X-tile load map: 256 thr x float4 covering 64 rows x 16 k
    const int lr  = tid >> 2;
    const int lc4 = (tid & 3) << 2;
    int slot_l = m0 + lr;
    int xrow;
    if (gathered) xrow = (slot_l < M) ? tok_list[e * N_TOK + slot_l] : 0;
    else          xrow = slot_l;
    const float* xptr = X + (size_t)xrow * HDIM;

    // W-tile load map: 256 thr x float4 covering 16 k x 64 n
    const int wk = tid >> 4;
    const int wn = (tid & 15) << 2;

    float accg[4][4] = {{0.f}};
    float accu[4][4] = {{0.f}};

    for (int k0 = 0; k0 < HDIM; k0 += BK) {
        float4 xv = *reinterpret_cast<const float4*>(xptr + k0 + lc4);
        float4 gv = *reinterpret_cast<const float4*>(Wg + (size_t)(k0 + wk) * Icols + n0 + wn);
        float4 uv = *reinterpret_cast<const float4*>(Wu + (size_t)(k0 + wk) * Icols + n0 + wn);
        __syncthreads();
        Xs[lc4 + 0][lr] = xv.x;
        Xs[lc4 + 1][lr] = xv.y;
        Xs[lc4 + 2][lr] = xv.z;
        Xs[lc4 + 3][lr] = xv.w;
        *reinterpret_cast<float4*>(&Gs[wk][wn]) = gv;
        *reinterpret_cast<float4*>(&Us[wk][wn]) = uv;
        __syncthreads();
#pragma unroll
        for (int kk = 0; kk < BK; ++kk) {
            float4 a4 = *reinterpret_cast<const float4*>(&Xs[kk][ty << 2]);
            float4 g4 = *reinterpret_cast<const float4*>(&Gs[kk][tx << 2]);
            float4 u4 = *reinterpret_cast<const float4*>(&Us[kk][tx << 2]);
            float av[4] = {a4.x, a4.y, a4.z, a4.w};
            float gw[4] = {g4.x, g4.y, g4.z, g4.w};
            float uw[4] = {u4.x, u4.y, u4.z, u4.w};
#pragma unroll
            for (int i = 0; i < 4; ++i)
#pragma unroll
                for (int j = 0; j < 4; ++j) {
                    accg[i][j] += av[i] * gw[j];
                    accu[i][j] += av[i] * uw[j];
                }
        }
    }

#pragma unroll
    for (int i = 0; i < 4; ++i) {
        int slot = m0 + (ty << 2) + i;
        if (slot < M) {
            float4 o;
            float v[4];
#pragma unroll
            for (int j = 0; j < 4; ++j) {
                float g = accg[i][j];
                float u = accu[i][j];
                v[j] = (g / (1.f + expf(-g))) * u;
            }
            o.x = v[0]; o.y = v[1]; o.z = v[2]; o.w = v[3];
            *reinterpret_cast<float4*>(Y + (size_t)(yb + slot) * Icols + n0 + (tx << 2)) = o;
        }
    }
}

// ------------------------------------------------- shared down (C = A@B) ----
__global__ __launch_bounds__(NTHREADS)
void down_plain_kernel(const float* __restrict__ A,   // [N_TOK, SIDIM]
                       const float* __restrict__ B,   // [SIDIM, HDIM]
                       float* __restrict__ out)       // [N_TOK, HDIM] (write)
{
    const int m0 = blockIdx.y * BM;
    const int n0 = blockIdx.x * BN;

    __shared__ float As[BK][BM + 4];
    __shared__ float Bs[BK][BN + 4];

    const int tid = threadIdx.x;
    const int tx = tid & 15;
    const int ty = tid >> 4;
    const int lr  = tid >> 2;
    const int lc4 = (tid & 3) << 2;
    const int wk = tid >> 4;
    const int wn = (tid & 15) << 2;

    const float* aptr = A + (size_t)(m0 + lr) * SIDIM;
    float acc[4][4] = {{0.f}};

    for (int k0 = 0; k0 < SIDIM; k0 += BK) {
        float4 av = *reinterpret_cast<const float4*>(aptr + k0 + lc4);
        float4 bv = *reinterpret_cast<const float4*>(B + (size_t)(k0 + wk) * HDIM + n0 + wn);
        __syncthreads();
        As[lc4 + 0][lr] = av.x;
        As[lc4 + 1][lr] = av.y;
        As[lc4 + 2][lr] = av.z;
        As[lc4 + 3][lr] = av.w;
        *reinterpret_cast<float4*>(&Bs[wk][wn]) = bv;
        __syncthreads();
#pragma unroll
        for (int kk = 0; kk < BK; ++kk) {
            float4 a4 = *reinterpret_cast<const float4*>(&As[kk][ty << 2]);
            float4 b4 = *reinterpret_cast<const float4*>(&Bs[kk][tx << 2]);
            float av2[4] = {a4.x, a4.y, a4.z, a4.w};
            float bv2[4] = {b4.x, b4.y, b4.z, b4.w};
#pragma unroll
            for (int i = 0; i < 4; ++i)
#pragma unroll
                for (int j = 0; j < 4; ++j)
                    acc[i][j] += av2[i] * bv2[j];
        }
    }

#pragma unroll
    for (int i = 0; i < 4; ++i) {
        float4 o;
        o.x = acc[i][0]; o.y = acc[i][1]; o.z = acc[i][2]; o.w = acc[i][3];
        *reinterpret_cast<float4*>(out + (size_t)(m0 + (ty << 2) + i) * HDIM + n0 + (tx << 2)) = o;
    }
}

// --------------------------------- expert down: out += wt * (Y @ Wd[e]) ----
__global__ __launch_bounds__(NTHREADS)
void down_scatter_kernel(const float* __restrict__ Y,      // [N_TOK*2, IDIM] compacted
                         const float* __restrict__ WdAll,  // [E, IDIM, HDIM]
                         float* __restrict__ out,
                         const int* __restrict__ cnt,
                         const int* __restrict__ base,
                         const int* __restrict__ tok_list,
                         const float* __restrict__ wt_list)
{
    const int e  = blockIdx.z;
    const int m0 = blockIdx.y * BM;
    const int n0 = blockIdx.x * BN;
    const int M = cnt[e];
    if (m0 >= M) return;
    const float* Wd = WdAll + (size_t)e * IDIM * HDIM;
    const int yb = base[e];

    __shared__ float As[BK][BM + 4];
    __shared__ float Bs[BK][BN + 4];

    const int tid = threadIdx.x;
    const int tx = tid & 15;
    const int ty = tid >> 4;
    const int lr  = tid >> 2;
    const int lc4 = (tid & 3) << 2;
    const int wk = tid >> 4;
    const int wn = (tid & 15) << 2;

    int slot_l = m0 + lr;
    int arow = yb + ((slot_l < M) ? slot_l : 0);
    const float* aptr = Y + (size_t)arow * IDIM;

    float acc[4][4] = {{0.f}};

    for (int k0 = 0; k0 < IDIM; k0 += BK) {
        float4 av = *reinterpret_cast<const float4*>(aptr + k0 + lc4);
        float4 bv = *reinterpret_cast<const float4*>(Wd + (size_t)(k0 + wk) * HDIM + n0 + wn);
        __syncthreads();
        As[lc4 + 0][lr] = av.x;
        As[lc4 + 1][lr] = av.y;
        As[lc4 + 2][lr] = av.z;
        As[lc4 + 3][lr] = av.w;
        *reinterpret_cast<float4*>(&Bs[wk][wn]) = bv;
        __syncthreads();
#pragma unroll
        for (int kk = 0; kk < BK; ++kk) {
            float4 a4 = *reinterpret_cast<const float4*>(&As[kk][ty << 2]);
            float4 b4 = *reinterpret_cast<const float4*>(&Bs[kk][tx << 2]);
            float av2[4] = {a4.x, a4.y, a4.z, a4.w};
            float bv2[4] = {b4.x, b4.y, b4.z, b4.w};
#pragma unroll
            for (int i = 0; i < 4; ++i)
#pragma unroll
                for (int j = 0; j < 4; ++j)
                    acc[i][j] += av2[i] * bv2[j];
        }
    }

#pragma unroll
    for (int i = 0; i < 4; ++i) {
        int slot = m0 + (ty << 2) + i;
        if (slot < M) {
            int tok = tok_list[e * N_TOK + slot];
            float wt = wt_list[e * N_TOK + slot];
            float* orow = out + (size_t)tok * HDIM + n0 + (tx << 2);
#pragma unroll
            for (int j = 0; j < 4; ++j)
                atomicAdd(orow + j, wt * acc[i][j]);
        }
    }
}

// ------------------------------------------------------------------ launch --
extern "C" void kernel_launch(void* const* d_in, const int* in_sizes, int n_in,
                              void* d_out, int out_size, void* d_ws, size_t ws_size,
                              hipStream_t stream)
{
    const float* x       = (const float*)d_in[0];
    const float* rw      = (const float*)d_in[1];
    const float* w_gate  = (const float*)d_in[2];
    const float* w_up    = (const float*)d_in[3];
    const float* w_down  = (const float*)d_in[4];
    const float* ws_gate = (const float*)d_in[5];
    const float* ws_up   = (const float*)d_in[6];
    const float* ws_down = (const float*)d_in[7];

    float* out    = (float*)d_out;                       // [N_TOK, HDIM]
    float* logits = out + (size_t)N_TOK * HDIM;          // [N_TOK, NEXP]

    // workspace layout (~34 MB)
    char* w = (char*)d_ws;
    int* cnt      = (int*)w;                             // 16
    int* base     = cnt + 16;                            // 16
    int* tok_list = base + 16;                           // E*N
    float* wt_list = (float*)(tok_list + NEXP * N_TOK);  // E*N
    uintptr_t p = (uintptr_t)(wt_list + NEXP * N_TOK);
    p = (p + 255) & ~(uintptr_t)255;
    float* A_shared = (float*)p;                         // [N_TOK, SIDIM]
    float* Ybuf     = A_shared + (size_t)N_TOK * SIDIM;  // [N_TOK*2, IDIM]

    hipMemsetAsync(cnt, 0, 16 * sizeof(int), stream);

    router_kernel<<<dim3(N_TOK), dim3(NTHREADS), 0, stream>>>(
        x, rw, logits, cnt, tok_list, wt_list);
    prefix_kernel<<<dim3(1), dim3(64), 0, stream>>>(cnt, base);

    // shared expert: A = silu(x@ws_gate) * (x@ws_up); out = A @ ws_down
    dual_swiglu_kernel<<<dim3(SIDIM / BN, N_TOK / BM, 1), dim3(NTHREADS), 0, stream>>>(
        x, ws_gate, ws_up, A_shared, nullptr, nullptr, nullptr, SIDIM);
    down_plain_kernel<<<dim3(HDIM / BN, N_TOK / BM, 1), dim3(NTHREADS), 0, stream>>>(
        A_shared, ws_down, out);

    // sparse experts (stream-ordered after down_plain's full write of `out`)
    dual_swiglu_kernel<<<dim3(IDIM / BN, N_TOK / BM, NEXP), dim3(NTHREADS), 0, stream>>>(
        x, w_gate, w_up, Ybuf, cnt, base, tok_list, IDIM);
    down_scatter_kernel<<<dim3(HDIM / BN, N_TOK / BM, NEXP), dim3(NTHREADS), 0, stream>>>(
        Ybuf, w_down, out, cnt, base, tok_list, wt_list);
}

// Round 2
// 746.051 us; speedup vs baseline: 2.4289x; 2.4289x over previous
//
#include <hip/hip_runtime.h>
#include <cstdint>
#include <cstddef>
#include <cmath>

#define N_TOK 2048
#define HDIM  2048
#define NEXP  16
#define IDIM  1024
#define SIDIM 2048
#define NTHREADS 256

typedef __attribute__((ext_vector_type(8))) short bf16x8;
typedef __attribute__((ext_vector_type(4))) float f32x4;

__device__ __forceinline__ uint32_t f2bf_u(float f) {
    union { float f; uint32_t u; } v; v.f = f;
    return (v.u + 0x7FFFu + ((v.u >> 16) & 1u)) >> 16;   // RNE
}
__device__ __forceinline__ uint32_t pack2bf(float lo, float hi) {
    return f2bf_u(lo) | (f2bf_u(hi) << 16);
}

// ---------------------------------------------------------------- router ----
// fp32 throughout: top-2 selection must not be perturbed by bf16 rounding.
__global__ __launch_bounds__(NTHREADS)
void router_kernel(const float* __restrict__ x,
                   const float* __restrict__ rw,
                   float* __restrict__ logits_out,
                   int* __restrict__ cnt,
                   int* __restrict__ tok_list,
                   float* __restrict__ wt_list)
{
    const int n = blockIdx.x;
    const int tid = threadIdx.x;
    const float* xr = x + (size_t)n * HDIM;

    float acc[NEXP];
#pragma unroll
    for (int e = 0; e < NEXP; ++e) acc[e] = 0.f;

    for (int h = tid; h < HDIM; h += NTHREADS) {
        float xv = xr[h];
#pragma unroll
        for (int e = 0; e < NEXP; ++e) acc[e] += xv * rw[(size_t)e * HDIM + h];
    }

    __shared__ float red[NEXP][NTHREADS];
#pragma unroll
    for (int e = 0; e < NEXP; ++e) red[e][tid] = acc[e];
    __syncthreads();
    for (int s = NTHREADS / 2; s > 0; s >>= 1) {
        if (tid < s) {
#pragma unroll
            for (int e = 0; e < NEXP; ++e) red[e][tid] += red[e][tid + s];
        }
        __syncthreads();
    }

    if (tid < NEXP) logits_out[(size_t)n * NEXP + tid] = red[tid][0];

    if (tid == 0) {
        float l[NEXP];
#pragma unroll
        for (int e = 0; e < NEXP; ++e) l[e] = red[e][0];
        int e0 = 0;
#pragma unroll
        for (int e = 1; e < NEXP; ++e) if (l[e] > l[e0]) e0 = e;
        int e1 = (e0 == 0) ? 1 : 0;
#pragma unroll
        for (int e = 0; e < NEXP; ++e)
            if (e != e0 && l[e] > l[e1]) e1 = e;
        float t = expf(l[e1] - l[e0]);
        float s = 1.f + t;
        float rw0 = 1.f / s;
        float rw1 = t / s;
        int p0 = atomicAdd(&cnt[e0], 1);
        tok_list[e0 * N_TOK + p0] = n;
        wt_list[e0 * N_TOK + p0] = rw0;
        int p1 = atomicAdd(&cnt[e1], 1);
        tok_list[e1 * N_TOK + p1] = n;
        wt_list[e1 * N_TOK + p1] = rw1;
    }
}

__global__ void prefix_kernel(const int* __restrict__ cnt, int* __restrict__ base)
{
    if (threadIdx.x == 0) {
        int s = 0;
        for (int e = 0; e < NEXP; ++e) { base[e] = s; s += cnt[e]; }
    }
}

// -------------------------------------- MFMA dual GEMM + SwiGLU (bf16 out) --
// Y[yb+m][n] = bf16( silu(X@Wg) * (X@Wu) ).  Tile: 128m x 64n(each) x 32k.
// 4 waves in 2x2; wave tile 64m x 32n per matrix.
__global__ __launch_bounds__(NTHREADS)
void dual_swiglu_mfma(const float* __restrict__ X,
                      const float* __restrict__ WgAll,
                      const float* __restrict__ WuAll,
                      unsigned short* __restrict__ Y,   // bf16 out [rows][Icols]
                      const int* __restrict__ cnt,
                      const int* __restrict__ base,
                      const int* __restrict__ tok_list,
                      const int Icols)
{
    const int e  = blockIdx.z;
    const int m0 = blockIdx.y * 128;
    const int n0 = blockIdx.x * 64;
    const bool gathered = (tok_list != nullptr);
    const int M = gathered ? cnt[e] : N_TOK;
    if (m0 >= M) return;
    const float* Wg = WgAll + (size_t)e * HDIM * Icols;
    const float* Wu = WuAll + (size_t)e * HDIM * Icols;
    const int yb = gathered ? base[e] : 0;

    __shared__ short As[128][40];   // [m][k], pad->40 shorts (80 B rows, 16B-aligned)
    __shared__ short Gs[64][40];    // [n][k] (transposed W)
    __shared__ short Us[64][40];

    const int tid  = threadIdx.x;
    const int lane = tid & 63;
    const int wave = tid >> 6;
    const int wm   = wave >> 1;     // 0..1 (m-half)
    const int wn   = wave & 1;      // 0..1 (n-half)
    const int l15  = lane & 15;
    const int q    = lane >> 4;     // quad 0..3

    // A staging: thread -> (row=tid>>1, 16-elem half)
    const int ar = tid >> 1;
    const int ac = (tid & 1) * 16;
    const int slotA = m0 + ar;
    int xrow;
    if (gathered) xrow = tok_list[e * N_TOK + ((slotA < M) ? slotA : 0)];
    else          xrow = slotA;
    const float* xp = X + (size_t)xrow * HDIM + ac;

    // W staging: thread -> (n-group of 4, k-pair). 64n x 32k = 2048 elems.
    const int wng = (tid & 15) << 2;   // n offset 0..60
    const int wkp = (tid >> 4) << 1;   // k offset 0..30 (even)
    const float* gp = Wg + (size_t)wkp * Icols + n0 + wng;
    const float* up = Wu + (size_t)wkp * Icols + n0 + wng;

    f32x4 accg[4][2], accu[4][2];
#pragma unroll
    for (int i = 0; i < 4; ++i)
#pragma unroll
        for (int j = 0; j < 2; ++j) {
            accg[i][j] = (f32x4){0.f, 0.f, 0.f, 0.f};
            accu[i][j] = (f32x4){0.f, 0.f, 0.f, 0.f};
        }

    for (int k0 = 0; k0 < HDIM; k0 += 32) {
        // global loads (fp32)
        const float* xk = xp + k0;
        float4 xa = *(const float4*)(xk + 0);
        float4 xb = *(const float4*)(xk + 4);
        float4 xc = *(const float4*)(xk + 8);
        float4 xd = *(const float4*)(xk + 12);
        const float* gk = gp + (size_t)k0 * Icols;
        float4 g0 = *(const float4*)(gk);
        float4 g1 = *(const float4*)(gk + Icols);
        const float* uk = up + (size_t)k0 * Icols;
        float4 u0 = *(const float4*)(uk);
        float4 u1 = *(const float4*)(uk + Icols);

        __syncthreads();
        // A: 16 bf16 contiguous
        {
            uint4 w0 = make_uint4(pack2bf(xa.x, xa.y), pack2bf(xa.z, xa.w),
                                  pack2bf(xb.x, xb.y), pack2bf(xb.z, xb.w));
            uint4 w1 = make_uint4(pack2bf(xc.x, xc.y), pack2bf(xc.z, xc.w),
                                  pack2bf(xd.x, xd.y), pack2bf(xd.z, xd.w));
            *reinterpret_cast<uint4*>(&As[ar][ac])     = w0;
            *reinterpret_cast<uint4*>(&As[ar][ac + 8]) = w1;
        }
        // W transpose: Gs[n][k] = Wg[k0+k][n0+n]
        ((uint32_t*)&Gs[wng + 0][wkp])[0] = pack2bf(g0.x, g1.x);
        ((uint32_t*)&Gs[wng + 1][wkp])[0] = pack2bf(g0.y, g1.y);
        ((uint32_t*)&Gs[wng + 2][wkp])[0] = pack2bf(g0.z, g1.z);
        ((uint32_t*)&Gs[wng + 3][wkp])[0] = pack2bf(g0.w, g1.w);
        ((uint32_t*)&Us[wng + 0][wkp])[0] = pack2bf(u0.x, u1.x);
        ((uint32_t*)&Us[wng + 1][wkp])[0] = pack2bf(u0.y, u1.y);
        ((uint32_t*)&Us[wng + 2][wkp])[0] = pack2bf(u0.z, u1.z);
        ((uint32_t*)&Us[wng + 3][wkp])[0] = pack2bf(u0.w, u1.w);
        __syncthreads();

        bf16x8 af[4], bg[2], bu[2];
#pragma unroll
        for (int i = 0; i < 4; ++i)
            af[i] = *reinterpret_cast<const bf16x8*>(&As[wm * 64 + i * 16 + l15][q * 8]);
#pragma unroll
        for (int j = 0; j < 2; ++j) {
            bg[j] = *reinterpret_cast<const bf16x8*>(&Gs[wn * 32 + j * 16 + l15][q * 8]);
            bu[j] = *reinterpret_cast<const bf16x8*>(&Us[wn * 32 + j * 16 + l15][q * 8]);
        }
#pragma unroll
        for (int i = 0; i < 4; ++i)
#pragma unroll
            for (int j = 0; j < 2; ++j) {
                accg[i][j] = __builtin_amdgcn_mfma_f32_16x16x32_bf16(af[i], bg[j], accg[i][j], 0, 0, 0);
                accu[i][j] = __builtin_amdgcn_mfma_f32_16x16x32_bf16(af[i], bu[j], accu[i][j], 0, 0, 0);
            }
    }

    // epilogue: silu(g)*u -> bf16
#pragma unroll
    for (int i = 0; i < 4; ++i) {
#pragma unroll
        for (int r = 0; r < 4; ++r) {
            const int slot = m0 + wm * 64 + i * 16 + q * 4 + r;
            if (slot < M) {
                unsigned short* yrow = Y + (size_t)(yb + slot) * Icols;
#pragma unroll
                for (int j = 0; j < 2; ++j) {
                    const int col = n0 + wn * 32 + j * 16 + l15;
                    float g = accg[i][j][r];
                    float u = accu[i][j][r];
                    float y = (g / (1.f + expf(-g))) * u;
                    yrow[col] = (unsigned short)f2bf_u(y);
                }
            }
        }
    }
}

// -------------------------------- MFMA down GEMM (bf16 A, fp32 W, fp32 out) --
// plain  (tok_list==null): out[m][n]  = A[m] @ W        (overwrites)
// scatter(tok_list!=null): out[tok[m]][n] += wt[m] * (A[yb+m] @ W[e])
// Tile: 128m x 128n x 32k; 4 waves 2x2; wave tile 64x64.
__global__ __launch_bounds__(NTHREADS)
void down_mfma(const unsigned short* __restrict__ A,  // bf16 [rows][K]
               const float* __restrict__ WdAll,       // [E?][K][HDIM]
               float* __restrict__ out,
               const int* __restrict__ cnt,
               const int* __restrict__ base,
               const int* __restrict__ tok_list,
               const float* __restrict__ wt_list,
               const int K)
{
    const int e  = blockIdx.z;
    const int m0 = blockIdx.y * 128;
    const int n0 = blockIdx.x * 128;
    const bool scatter = (tok_list != nullptr);
    const int M = scatter ? cnt[e] : N_TOK;
    if (m0 >= M) return;
    const float* Wd = WdAll + (size_t)e * K * HDIM;
    const int yb = scatter ? base[e] : 0;

    __shared__ short As[128][40];
    __shared__ short Bs[128][40];   // [n][k] transposed

    const int tid  = threadIdx.x;
    const int lane = tid & 63;
    const int wave = tid >> 6;
    const int wm   = wave >> 1;
    const int wn   = wave & 1;
    const int l15  = lane & 15;
    const int q    = lane >> 4;

    // A staging (bf16 passthrough)
    const int ar = tid >> 1;
    const int ac = (tid & 1) * 16;
    const int slotA = m0 + ar;
    const int arow = yb + ((slotA < M) ? slotA : 0);
    const unsigned short* ap = A + (size_t)arow * K + ac;

    // B staging: thread -> (n-group of 4, k-group of 4). 128n x 32k.
    const int bn = (tid & 31) << 2;  // 0..124
    const int bk = (tid >> 5) << 2;  // 0..28
    const float* bp = Wd + (size_t)bk * HDIM + n0 + bn;

    f32x4 acc[4][4];
#pragma unroll
    for (int i = 0; i < 4; ++i)
#pragma unroll
        for (int j = 0; j < 4; ++j) acc[i][j] = (f32x4){0.f, 0.f, 0.f, 0.f};

    for (int k0 = 0; k0 < K; k0 += 32) {
        uint4 a0 = *(const uint4*)(ap + k0);
        uint4 a1 = *(const uint4*)(ap + k0 + 8);
        const float* bkp = bp + (size_t)k0 * HDIM;
        float4 b0 = *(const float4*)(bkp);
        float4 b1 = *(const float4*)(bkp + HDIM);
        float4 b2 = *(const float4*)(bkp + 2 * (size_t)HDIM);
        float4 b3 = *(const float4*)(bkp + 3 * (size_t)HDIM);

        __syncthreads();
        *reinterpret_cast<uint4*>(&As[ar][ac])     = a0;
        *reinterpret_cast<uint4*>(&As[ar][ac + 8]) = a1;
        {   // Bs[n][k] = W[k0+k][n0+n]
            uint2 w;
            w.x = pack2bf(b0.x, b1.x); w.y = pack2bf(b2.x, b3.x);
            *reinterpret_cast<uint2*>(&Bs[bn + 0][bk]) = w;
            w.x = pack2bf(b0.y, b1.y); w.y = pack2bf(b2.y, b3.y);
            *reinterpret_cast<uint2*>(&Bs[bn + 1][bk]) = w;
            w.x = pack2bf(b0.z, b1.z); w.y = pack2bf(b2.z, b3.z);
            *reinterpret_cast<uint2*>(&Bs[bn + 2][bk]) = w;
            w.x = pack2bf(b0.w, b1.w); w.y = pack2bf(b2.w, b3.w);
            *reinterpret_cast<uint2*>(&Bs[bn + 3][bk]) = w;
        }
        __syncthreads();

        bf16x8 af[4], bf[4];
#pragma unroll
        for (int i = 0; i < 4; ++i)
            af[i] = *reinterpret_cast<const bf16x8*>(&As[wm * 64 + i * 16 + l15][q * 8]);
#pragma unroll
        for (int j = 0; j < 4; ++j)
            bf[j] = *reinterpret_cast<const bf16x8*>(&Bs[wn * 64 + j * 16 + l15][q * 8]);
#pragma unroll
        for (int i = 0; i < 4; ++i)
#pragma unroll
            for (int j = 0; j < 4; ++j)
                acc[i][j] = __builtin_amdgcn_mfma_f32_16x16x32_bf16(af[i], bf[j], acc[i][j], 0, 0, 0);
    }

#pragma unroll
    for (int i = 0; i < 4; ++i) {
#pragma unroll
        for (int r = 0; r < 4; ++r) {
            const int slot = m0 + wm * 64 + i * 16 + q * 4 + r;
            if (slot >= M) continue;
            if (scatter) {
                const int tok = tok_list[e * N_TOK + slot];
                const float wt = wt_list[e * N_TOK + slot];
                float* orow = out + (size_t)tok * HDIM;
#pragma unroll
                for (int j = 0; j < 4; ++j) {
                    const int col = n0 + wn * 64 + j * 16 + l15;
                    atomicAdd(&orow[col], wt * acc[i][j][r]);
                }
            } else {
                float* orow = out + (size_t)slot * HDIM;
#pragma unroll
                for (int j = 0; j < 4; ++j) {
                    const int col = n0 + wn * 64 + j * 16 + l15;
                    orow[col] = acc[i][j][r];
                }
            }
        }
    }
}

// ------------------------------------------------------------------ launch --
extern "C" void kernel_launch(void* const* d_in, const int* in_sizes, int n_in,
                              void* d_out, int out_size, void* d_ws, size_t ws_size,
                              hipStream_t stream)
{
    const float* x       = (const float*)d_in[0];
    const float* rw      = (const float*)d_in[1];
    const float* w_gate  = (const float*)d_in[2];
    const float* w_up    = (const float*)d_in[3];
    const float* w_down  = (const float*)d_in[4];
    const float* ws_gate = (const float*)d_in[5];
    const float* ws_up   = (const float*)d_in[6];
    const float* ws_down = (const float*)d_in[7];

    float* out    = (float*)d_out;                       // [N_TOK, HDIM]
    float* logits = out + (size_t)N_TOK * HDIM;          // [N_TOK, NEXP]

    // workspace (~17.2 MB)
    char* w = (char*)d_ws;
    int* cnt      = (int*)w;                             // 16
    int* base     = cnt + 16;                            // 16
    int* tok_list = base + 16;                           // E*N
    float* wt_list = (float*)(tok_list + NEXP * N_TOK);  // E*N
    uintptr_t p = (uintptr_t)(wt_list + NEXP * N_TOK);
    p = (p + 255) & ~(uintptr_t)255;
    unsigned short* A_shared = (unsigned short*)p;                 // bf16 [N_TOK][SIDIM]
    unsigned short* Ybuf     = A_shared + (size_t)N_TOK * SIDIM;   // bf16 [N_TOK*2][IDIM]

    hipMemsetAsync(cnt, 0, 16 * sizeof(int), stream);

    router_kernel<<<dim3(N_TOK), dim3(NTHREADS), 0, stream>>>(
        x, rw, logits, cnt, tok_list, wt_list);
    prefix_kernel<<<dim3(1), dim3(64), 0, stream>>>(cnt, base);

    // shared expert
    dual_swiglu_mfma<<<dim3(SIDIM / 64, N_TOK / 128, 1), dim3(NTHREADS), 0, stream>>>(
        x, ws_gate, ws_up, A_shared, cnt, base, nullptr, SIDIM);
    down_mfma<<<dim3(HDIM / 128, N_TOK / 128, 1), dim3(NTHREADS), 0, stream>>>(
        A_shared, ws_down, out, cnt, base, nullptr, nullptr, SIDIM);

    // sparse experts (stream-ordered after the shared write of `out`)
    dual_swiglu_mfma<<<dim3(IDIM / 64, N_TOK / 128, NEXP), dim3(NTHREADS), 0, stream>>>(
        x, w_gate, w_up, Ybuf, cnt, base, tok_list, IDIM);
    down_mfma<<<dim3(HDIM / 128, N_TOK / 128, NEXP), dim3(NTHREADS), 0, stream>>>(
        Ybuf, w_down, out, cnt, base, tok_list, wt_list, IDIM);
}

// Round 3
// 713.345 us; speedup vs baseline: 2.5402x; 1.0458x over previous
//
#include <hip/hip_runtime.h>
#include <cstdint>
#include <cstddef>
#include <cmath>

#define N_TOK 2048
#define HDIM  2048
#define NEXP  16
#define IDIM  1024
#define SIDIM 2048
#define NTHREADS 256

typedef __attribute__((ext_vector_type(8))) short bf16x8;
typedef __attribute__((ext_vector_type(4))) float f32x4;

__device__ __forceinline__ uint32_t f2bf_u(float f) {
    union { float f; uint32_t u; } v; v.f = f;
    return (v.u + 0x7FFFu + ((v.u >> 16) & 1u)) >> 16;   // RNE
}
__device__ __forceinline__ uint32_t pack2bf(float lo, float hi) {
    return f2bf_u(lo) | (f2bf_u(hi) << 16);
}

// XOR-swizzled 16B-chunk index for a tile with 64B rows (4 chunks/row).
// Conflict-free (8-access/bank floor) for both n-major b128 staging writes
// and MFMA-fragment b128 reads; keeps 16B alignment with zero padding.
__device__ __forceinline__ int swz(int row, int c) {
    return row * 4 + (c ^ ((row >> 1) & 3));
}

// ------------------------------------------------------------ x -> bf16 ----
__global__ __launch_bounds__(NTHREADS)
void convert_x_kernel(const float* __restrict__ x, unsigned short* __restrict__ xb)
{
    const size_t i = ((size_t)blockIdx.x * NTHREADS + threadIdx.x) * 8;
    float4 a = *(const float4*)(x + i);
    float4 b = *(const float4*)(x + i + 4);
    uint4 w = make_uint4(pack2bf(a.x, a.y), pack2bf(a.z, a.w),
                         pack2bf(b.x, b.y), pack2bf(b.z, b.w));
    *(uint4*)(xb + i) = w;
}

// ---------------------------------------------------------------- router ----
// fp32 throughout: top-2 selection must not be perturbed by bf16 rounding.
__global__ __launch_bounds__(NTHREADS)
void router_kernel(const float* __restrict__ x,
                   const float* __restrict__ rw,
                   float* __restrict__ logits_out,
                   int* __restrict__ cnt,
                   int* __restrict__ tok_list,
                   float* __restrict__ wt_list)
{
    const int n = blockIdx.x;
    const int tid = threadIdx.x;
    const float* xr = x + (size_t)n * HDIM;

    float acc[NEXP];
#pragma unroll
    for (int e = 0; e < NEXP; ++e) acc[e] = 0.f;

    for (int h = tid; h < HDIM; h += NTHREADS) {
        float xv = xr[h];
#pragma unroll
        for (int e = 0; e < NEXP; ++e) acc[e] += xv * rw[(size_t)e * HDIM + h];
    }

    __shared__ float red[NEXP][NTHREADS];
#pragma unroll
    for (int e = 0; e < NEXP; ++e) red[e][tid] = acc[e];
    __syncthreads();
    for (int s = NTHREADS / 2; s > 0; s >>= 1) {
        if (tid < s) {
#pragma unroll
            for (int e = 0; e < NEXP; ++e) red[e][tid] += red[e][tid + s];
        }
        __syncthreads();
    }

    if (tid < NEXP) logits_out[(size_t)n * NEXP + tid] = red[tid][0];

    if (tid == 0) {
        float l[NEXP];
#pragma unroll
        for (int e = 0; e < NEXP; ++e) l[e] = red[e][0];
        int e0 = 0;
#pragma unroll
        for (int e = 1; e < NEXP; ++e) if (l[e] > l[e0]) e0 = e;
        int e1 = (e0 == 0) ? 1 : 0;
#pragma unroll
        for (int e = 0; e < NEXP; ++e)
            if (e != e0 && l[e] > l[e1]) e1 = e;
        float t = expf(l[e1] - l[e0]);
        float s = 1.f + t;
        float rw0 = 1.f / s;
        float rw1 = t / s;
        int p0 = atomicAdd(&cnt[e0], 1);
        tok_list[e0 * N_TOK + p0] = n;
        wt_list[e0 * N_TOK + p0] = rw0;
        int p1 = atomicAdd(&cnt[e1], 1);
        tok_list[e1 * N_TOK + p1] = n;
        wt_list[e1 * N_TOK + p1] = rw1;
    }
}

__global__ void prefix_kernel(const int* __restrict__ cnt, int* __restrict__ base)
{
    if (threadIdx.x == 0) {
        int s = 0;
        for (int e = 0; e < NEXP; ++e) { base[e] = s; s += cnt[e]; }
    }
}

// -------------------------------------- MFMA dual GEMM + SwiGLU (bf16 out) --
// Y[yb+m][n] = bf16( silu(X@Wg) * (X@Wu) ).  Tile: 128m x 64n x 32k.
// 4 waves 2x2; wave tile 64m x 32n per matrix. Register-prefetch pipeline.
__global__ __launch_bounds__(NTHREADS)
void dual_swiglu_mfma(const unsigned short* __restrict__ Xb,  // bf16 [N_TOK][HDIM]
                      const float* __restrict__ WgAll,
                      const float* __restrict__ WuAll,
                      unsigned short* __restrict__ Y,         // bf16 [rows][Icols]
                      const int* __restrict__ cnt,
                      const int* __restrict__ base,
                      const int* __restrict__ tok_list,
                      const int Icols)
{
    const int e  = blockIdx.z;
    const int m0 = blockIdx.y * 128;
    const int n0 = blockIdx.x * 64;
    const bool gathered = (tok_list != nullptr);
    const int M = gathered ? cnt[e] : N_TOK;
    if (m0 >= M) return;
    const float* Wg = WgAll + (size_t)e * HDIM * Icols;
    const float* Wu = WuAll + (size_t)e * HDIM * Icols;
    const int yb = gathered ? base[e] : 0;

    __shared__ short As[128 * 32];   // [m][k] swizzled
    __shared__ short Gs[64 * 32];    // [n][k] swizzled (transposed W)
    __shared__ short Us[64 * 32];

    const int tid  = threadIdx.x;
    const int lane = tid & 63;
    const int wave = tid >> 6;
    const int wm   = wave >> 1;
    const int wn   = wave & 1;
    const int l15  = lane & 15;
    const int q    = lane >> 4;

    // A staging: thread -> (row=tid>>1, chunk pair at*2, at*2+1)
    const int ar = tid >> 1;
    const int at = tid & 1;
    const int slotA = m0 + ar;
    int xrow;
    if (gathered) xrow = tok_list[e * N_TOK + ((slotA < M) ? slotA : (M - 1))];
    else          xrow = slotA;
    const unsigned short* xp = Xb + (size_t)xrow * HDIM + at * 16;

    // W staging: thread -> column n = tid&63, k-chunk c = tid>>6 (8 k each).
    // Column loads: lanes read consecutive n -> coalesced 256B per instr.
    const int wcn = tid & 63;
    const int wcc = tid >> 6;
    const float* gp = Wg + n0 + wcn;
    const float* up = Wu + n0 + wcn;

    f32x4 accg[4][2], accu[4][2];
#pragma unroll
    for (int i = 0; i < 4; ++i)
#pragma unroll
        for (int j = 0; j < 2; ++j) {
            accg[i][j] = (f32x4){0.f, 0.f, 0.f, 0.f};
            accu[i][j] = (f32x4){0.f, 0.f, 0.f, 0.f};
        }

    uint4 a0, a1;
    float g8[8], u8[8];
    auto ldtile = [&](int kk) {
        a0 = *(const uint4*)(xp + kk);
        a1 = *(const uint4*)(xp + kk + 8);
#pragma unroll
        for (int j = 0; j < 8; ++j) {
            g8[j] = gp[(size_t)(kk + wcc * 8 + j) * Icols];
            u8[j] = up[(size_t)(kk + wcc * 8 + j) * Icols];
        }
    };

    ldtile(0);
    for (int k0 = 0; k0 < HDIM; k0 += 32) {
        __syncthreads();
        *(uint4*)(As + swz(ar, at * 2 + 0) * 8) = a0;
        *(uint4*)(As + swz(ar, at * 2 + 1) * 8) = a1;
        uint4 gw = make_uint4(pack2bf(g8[0], g8[1]), pack2bf(g8[2], g8[3]),
                              pack2bf(g8[4], g8[5]), pack2bf(g8[6], g8[7]));
        uint4 uw = make_uint4(pack2bf(u8[0], u8[1]), pack2bf(u8[2], u8[3]),
                              pack2bf(u8[4], u8[5]), pack2bf(u8[6], u8[7]));
        *(uint4*)(Gs + swz(wcn, wcc) * 8) = gw;
        *(uint4*)(Us + swz(wcn, wcc) * 8) = uw;
        __syncthreads();

        int kn = k0 + 32;
        if (kn >= HDIM) kn = k0;     // redundant last load, keeps loop uniform
        ldtile(kn);                  // overlaps with MFMA below

        bf16x8 af[4], bg[2], bu[2];
#pragma unroll
        for (int i = 0; i < 4; ++i)
            af[i] = *(const bf16x8*)(As + swz(wm * 64 + i * 16 + l15, q) * 8);
#pragma unroll
        for (int j = 0; j < 2; ++j) {
            bg[j] = *(const bf16x8*)(Gs + swz(wn * 32 + j * 16 + l15, q) * 8);
            bu[j] = *(const bf16x8*)(Us + swz(wn * 32 + j * 16 + l15, q) * 8);
        }
#pragma unroll
        for (int i = 0; i < 4; ++i)
#pragma unroll
            for (int j = 0; j < 2; ++j) {
                accg[i][j] = __builtin_amdgcn_mfma_f32_16x16x32_bf16(af[i], bg[j], accg[i][j], 0, 0, 0);
                accu[i][j] = __builtin_amdgcn_mfma_f32_16x16x32_bf16(af[i], bu[j], accu[i][j], 0, 0, 0);
            }
    }

    // epilogue: silu(g)*u -> bf16
#pragma unroll
    for (int i = 0; i < 4; ++i) {
#pragma unroll
        for (int r = 0; r < 4; ++r) {
            const int slot = m0 + wm * 64 + i * 16 + q * 4 + r;
            if (slot < M) {
                unsigned short* yrow = Y + (size_t)(yb + slot) * Icols;
#pragma unroll
                for (int j = 0; j < 2; ++j) {
                    const int col = n0 + wn * 32 + j * 16 + l15;
                    float g = accg[i][j][r];
                    float u = accu[i][j][r];
                    float y = (g / (1.f + expf(-g))) * u;
                    yrow[col] = (unsigned short)f2bf_u(y);
                }
            }
        }
    }
}

// -------------------------------- MFMA down GEMM (bf16 A, fp32 W, fp32 out) --
// plain  (tok_list==null): out[m][n]  = A[m] @ W        (overwrites)
// scatter(tok_list!=null): out[tok[m]][n] += wt[m] * (A[yb+m] @ W[e])
// Tile: 64m x 128n x 32k; 4 waves 2x2; wave tile 32x64. Prefetch pipeline.
__global__ __launch_bounds__(NTHREADS)
void down_mfma(const unsigned short* __restrict__ A,  // bf16 [rows][K]
               const float* __restrict__ WdAll,       // [E?][K][HDIM]
               float* __restrict__ out,
               const int* __restrict__ cnt,
               const int* __restrict__ base,
               const int* __restrict__ tok_list,
               const float* __restrict__ wt_list,
               const int K)
{
    const int e  = blockIdx.z;
    const int m0 = blockIdx.y * 64;
    const int n0 = blockIdx.x * 128;
    const bool scatter = (tok_list != nullptr);
    const int M = scatter ? cnt[e] : N_TOK;
    if (m0 >= M) return;
    const float* Wd = WdAll + (size_t)e * K * HDIM;
    const int yb = scatter ? base[e] : 0;

    __shared__ short As[64 * 32];    // [m][k] swizzled
    __shared__ short Bs[128 * 32];   // [n][k] swizzled (transposed W)

    const int tid  = threadIdx.x;
    const int lane = tid & 63;
    const int wave = tid >> 6;
    const int wm   = wave >> 1;
    const int wn   = wave & 1;
    const int l15  = lane & 15;
    const int q    = lane >> 4;

    // A staging: thread -> (row=tid>>2, chunk tid&3), one uint4
    const int ar = tid >> 2;
    const int ac = tid & 3;
    const int slotA = m0 + ar;
    const int arow = yb + ((slotA < M) ? slotA : (M - 1));
    const unsigned short* ap = A + (size_t)arow * K + ac * 8;

    // B staging: thread -> column n = tid&127, chunk pair {2h, 2h+1}, h=tid>>7
    const int bn = tid & 127;
    const int bh = tid >> 7;
    const float* bp = Wd + n0 + bn;

    f32x4 acc[2][4];
#pragma unroll
    for (int i = 0; i < 2; ++i)
#pragma unroll
        for (int j = 0; j < 4; ++j) acc[i][j] = (f32x4){0.f, 0.f, 0.f, 0.f};

    uint4 a0;
    float b16[16];
    auto ldtile = [&](int kk) {
        a0 = *(const uint4*)(ap + kk);
#pragma unroll
        for (int c = 0; c < 2; ++c)
#pragma unroll
            for (int j = 0; j < 8; ++j)
                b16[c * 8 + j] = bp[(size_t)(kk + (bh * 2 + c) * 8 + j) * HDIM];
    };

    ldtile(0);
    for (int k0 = 0; k0 < K; k0 += 32) {
        __syncthreads();
        *(uint4*)(As + swz(ar, ac) * 8) = a0;
        uint4 w0 = make_uint4(pack2bf(b16[0], b16[1]), pack2bf(b16[2], b16[3]),
                              pack2bf(b16[4], b16[5]), pack2bf(b16[6], b16[7]));
        uint4 w1 = make_uint4(pack2bf(b16[8], b16[9]), pack2bf(b16[10], b16[11]),
                              pack2bf(b16[12], b16[13]), pack2bf(b16[14], b16[15]));
        *(uint4*)(Bs + swz(bn, bh * 2 + 0) * 8) = w0;
        *(uint4*)(Bs + swz(bn, bh * 2 + 1) * 8) = w1;
        __syncthreads();

        int kn = k0 + 32;
        if (kn >= K) kn = k0;
        ldtile(kn);

        bf16x8 af[2], bfr[4];
#pragma unroll
        for (int i = 0; i < 2; ++i)
            af[i] = *(const bf16x8*)(As + swz(wm * 32 + i * 16 + l15, q) * 8);
#pragma unroll
        for (int j = 0; j < 4; ++j)
            bfr[j] = *(const bf16x8*)(Bs + swz(wn * 64 + j * 16 + l15, q) * 8);
#pragma unroll
        for (int i = 0; i < 2; ++i)
#pragma unroll
            for (int j = 0; j < 4; ++j)
                acc[i][j] = __builtin_amdgcn_mfma_f32_16x16x32_bf16(af[i], bfr[j], acc[i][j], 0, 0, 0);
    }

#pragma unroll
    for (int i = 0; i < 2; ++i) {
#pragma unroll
        for (int r = 0; r < 4; ++r) {
            const int slot = m0 + wm * 32 + i * 16 + q * 4 + r;
            if (slot >= M) continue;
            if (scatter) {
                const int tok = tok_list[e * N_TOK + slot];
                const float wt = wt_list[e * N_TOK + slot];
                float* orow = out + (size_t)tok * HDIM;
#pragma unroll
                for (int j = 0; j < 4; ++j) {
                    const int col = n0 + wn * 64 + j * 16 + l15;
                    atomicAdd(&orow[col], wt * acc[i][j][r]);
                }
            } else {
                float* orow = out + (size_t)slot * HDIM;
#pragma unroll
                for (int j = 0; j < 4; ++j) {
                    const int col = n0 + wn * 64 + j * 16 + l15;
                    orow[col] = acc[i][j][r];
                }
            }
        }
    }
}

// ------------------------------------------------------------------ launch --
extern "C" void kernel_launch(void* const* d_in, const int* in_sizes, int n_in,
                              void* d_out, int out_size, void* d_ws, size_t ws_size,
                              hipStream_t stream)
{
    const float* x       = (const float*)d_in[0];
    const float* rw      = (const float*)d_in[1];
    const float* w_gate  = (const float*)d_in[2];
    const float* w_up    = (const float*)d_in[3];
    const float* w_down  = (const float*)d_in[4];
    const float* ws_gate = (const float*)d_in[5];
    const float* ws_up   = (const float*)d_in[6];
    const float* ws_down = (const float*)d_in[7];

    float* out    = (float*)d_out;                       // [N_TOK, HDIM]
    float* logits = out + (size_t)N_TOK * HDIM;          // [N_TOK, NEXP]

    // workspace (~25 MB)
    char* w = (char*)d_ws;
    int* cnt      = (int*)w;                             // 16
    int* base     = cnt + 16;                            // 16
    int* tok_list = base + 16;                           // E*N
    float* wt_list = (float*)(tok_list + NEXP * N_TOK);  // E*N
    uintptr_t p = (uintptr_t)(wt_list + NEXP * N_TOK);
    p = (p + 255) & ~(uintptr_t)255;
    unsigned short* Xb       = (unsigned short*)p;                 // bf16 [N_TOK][HDIM]
    unsigned short* A_shared = Xb + (size_t)N_TOK * HDIM;          // bf16 [N_TOK][SIDIM]
    unsigned short* Ybuf     = A_shared + (size_t)N_TOK * SIDIM;   // bf16 [N_TOK*2][IDIM]

    hipMemsetAsync(cnt, 0, 16 * sizeof(int), stream);

    convert_x_kernel<<<dim3((N_TOK * HDIM) / (NTHREADS * 8)), dim3(NTHREADS), 0, stream>>>(x, Xb);
    router_kernel<<<dim3(N_TOK), dim3(NTHREADS), 0, stream>>>(
        x, rw, logits, cnt, tok_list, wt_list);
    prefix_kernel<<<dim3(1), dim3(64), 0, stream>>>(cnt, base);

    // shared expert
    dual_swiglu_mfma<<<dim3(SIDIM / 64, N_TOK / 128, 1), dim3(NTHREADS), 0, stream>>>(
        Xb, ws_gate, ws_up, A_shared, cnt, base, nullptr, SIDIM);
    down_mfma<<<dim3(HDIM / 128, N_TOK / 64, 1), dim3(NTHREADS), 0, stream>>>(
        A_shared, ws_down, out, cnt, base, nullptr, nullptr, SIDIM);

    // sparse experts (stream-ordered after the shared write of `out`)
    dual_swiglu_mfma<<<dim3(IDIM / 64, N_TOK / 128, NEXP), dim3(NTHREADS), 0, stream>>>(
        Xb, w_gate, w_up, Ybuf, cnt, base, tok_list, IDIM);
    down_mfma<<<dim3(HDIM / 128, N_TOK / 64, NEXP), dim3(NTHREADS), 0, stream>>>(
        Ybuf, w_down, out, cnt, base, tok_list, wt_list, IDIM);
}